// Round 1
// baseline (167.276 us; speedup 1.0000x reference)
//
#include <hip/hip_runtime.h>
#include <hip/hip_bf16.h>

#define B_ 2
#define S_ 2048
#define D_ 1024
#define H_ 16
#define HD_ 64

typedef __attribute__((ext_vector_type(8))) short short8;
typedef __attribute__((ext_vector_type(4))) short short4v;
typedef __attribute__((ext_vector_type(4))) float float4v;

typedef const __attribute__((address_space(1))) void* gas_ptr;
typedef __attribute__((address_space(3))) void* las_ptr;

static __device__ inline void gl_lds16(const void* g, void* l) {
  __builtin_amdgcn_global_load_lds((gas_ptr)g, (las_ptr)l, 16, 0, 0);
}

static __device__ inline float b2f(__hip_bfloat16 h) { return __bfloat162float(h); }

static __device__ inline short f2bs(float x) {
  __hip_bfloat16 h = __float2bfloat16(x);
  union { __hip_bfloat16 h; short s; } u; u.h = h; return u.s;
}
static __device__ inline float bs2f(short s) {
  union { short s; __hip_bfloat16 h; } u; u.s = s; return __bfloat162float(u.h);
}
// packed f32x4 -> bf16x4 (v_cvt_pk_bf16_f32 x2)
static __device__ inline short4v pk4(float a, float b, float c, float d) {
  union { __hip_bfloat162 h[2]; short4v s; } u;
  u.h[0] = __float22bfloat162_rn(float2{a, b});
  u.h[1] = __float22bfloat162_rn(float2{c, d});
  return u.s;
}

static __device__ inline float4v mfma32(short8 a, short8 b, float4v c) {
  return __builtin_amdgcn_mfma_f32_16x16x32_bf16(a, b, c, 0, 0, 0);
}
// v_mfma_f32_16x16x16_bf16 — "_1k" builtin, present on gfx950.
static __device__ inline float4v mfma16(short4v a, short4v b, float4v c) {
  return __builtin_amdgcn_mfma_f32_16x16x16bf16_1k(a, b, c, 0, 0, 0);
}

// ------- Stage A: W fp32 [k][n] -> Wt bf16 [n][k] -------
__global__ __launch_bounds__(256) void pre(
    const float* __restrict__ Wq, const float* __restrict__ Wk,
    __hip_bfloat16* __restrict__ Wqt, __hip_bfloat16* __restrict__ Wkt) {
  const float* W = blockIdx.z ? Wk : Wq;
  __hip_bfloat16* Wt = blockIdx.z ? Wkt : Wqt;
  __shared__ float t[64][65];
  const int n0 = blockIdx.x * 64, k0 = blockIdx.y * 64;
  const int c = threadIdx.x & 63, r0 = threadIdx.x >> 6;
  for (int i = 0; i < 16; ++i) {
    const int r = i * 4 + r0;
    t[c][r] = W[(size_t)(k0 + r) * D_ + n0 + c];
  }
  __syncthreads();
  for (int i = 0; i < 16; ++i) {
    const int rr = i * 4 + r0;
    Wt[(size_t)(n0 + rr) * D_ + k0 + c] = __float2bfloat16(t[rr][c]);
  }
}

// ---- Stage B (fused GEMM+prep): 128x128 tile, 512 thr / 8 waves, XCD-PINNED.
__global__ __launch_bounds__(512, 2) void gemm_fused(
    const float* __restrict__ hs,
    const __hip_bfloat16* __restrict__ Wqt, const __hip_bfloat16* __restrict__ Wkt,
    const float* __restrict__ bq, const float* __restrict__ bk,
    __hip_bfloat16* __restrict__ q_out, __hip_bfloat16* __restrict__ kt_out,
    __hip_bfloat16* __restrict__ vT) {
  const int id = blockIdx.x;
  const int mt = (id & 7) * 4 + ((id >> 3) & 3);  // m-tile 0..31, pinned by xcd
  const int nt = id >> 5;                          // n-block 0..7
  const int n0 = nt * 128, m0 = mt * 128;
  __shared__ __hip_bfloat16 As[2][128 * 32];
  __shared__ __hip_bfloat16 Bq[2][128 * 32];
  __shared__ __hip_bfloat16 Bk[2][128 * 32];
  const int tid = threadIdx.x, wid = tid >> 6, lane = tid & 63;
  const int wm = (wid >> 1) * 32, wn = (wid & 1) * 64;
  const int l15 = lane & 15, l4 = lane >> 4;
  const float4v zz = {0.f, 0.f, 0.f, 0.f};
  float4v accq[2][4], acck[2][4];
  for (int i = 0; i < 2; ++i)
    for (int j = 0; j < 4; ++j) { accq[i][j] = zz; acck[i][j] = zz; }
  const int lrow = wid * 16 + (lane >> 2);
  const int lk8 = (lane & 3) * 8;
  // preload chunk 0
  {
    const float* pa = hs + (size_t)(m0 + lrow) * D_ + lk8;
    const float4v a0 = ((const float4v*)pa)[0], a1 = ((const float4v*)pa)[1];
    short8 s;
    for (int j = 0; j < 4; ++j) { s[j] = f2bs(a0[j]); s[4 + j] = f2bs(a1[j]); }
    *(short8*)(As[0] + wid * 512 + lane * 8) = s;
    gl_lds16(Wqt + (size_t)(n0 + lrow) * D_ + lk8, Bq[0] + wid * 512);
    gl_lds16(Wkt + (size_t)(n0 + lrow) * D_ + lk8, Bk[0] + wid * 512);
  }
  int p = 0;
  for (int kb = 0; kb < 32; ++kb) {
    __syncthreads();  // buf[p] staged (vm+lgkm drained); prev frag reads done
    if (kb < 31) {
      const int kc = (kb + 1) * 32 + lk8;
      gl_lds16(Wqt + (size_t)(n0 + lrow) * D_ + kc, Bq[p ^ 1] + wid * 512);
      gl_lds16(Wkt + (size_t)(n0 + lrow) * D_ + kc, Bk[p ^ 1] + wid * 512);
      const float* pa = hs + (size_t)(m0 + lrow) * D_ + kc;
      const float4v a0 = ((const float4v*)pa)[0], a1 = ((const float4v*)pa)[1];
      short8 s;
      for (int j = 0; j < 4; ++j) { s[j] = f2bs(a0[j]); s[4 + j] = f2bs(a1[j]); }
      *(short8*)(As[p ^ 1] + wid * 512 + lane * 8) = s;
    }
    short8 af[2], bfq[4], bfk[4];
    const int fo = l4 * 8;
    for (int rt = 0; rt < 2; ++rt)
      af[rt] = *(const short8*)(As[p] + (wm + rt * 16 + l15) * 32 + fo);
    for (int ct = 0; ct < 4; ++ct) {
      bfq[ct] = *(const short8*)(Bq[p] + (wn + ct * 16 + l15) * 32 + fo);
      bfk[ct] = *(const short8*)(Bk[p] + (wn + ct * 16 + l15) * 32 + fo);
    }
    for (int rt = 0; rt < 2; ++rt)
      for (int ct = 0; ct < 4; ++ct) {
        accq[rt][ct] = mfma32(af[rt], bfq[ct], accq[rt][ct]);
        acck[rt][ct] = mfma32(af[rt], bfk[ct], acck[rt][ct]);
      }
    p ^= 1;
  }
  float bvq[4], bvk[4];
  for (int ct = 0; ct < 4; ++ct) {
    bvq[ct] = bq[n0 + wn + ct * 16 + l15];
    bvk[ct] = bk[n0 + wn + ct * 16 + l15];
  }
  for (int rt = 0; rt < 2; ++rt)
    for (int ct = 0; ct < 4; ++ct) {
      const int col = n0 + wn + ct * 16 + l15;
      const int h = col >> 6, d = col & 63;
      const int rowb = m0 + wm + rt * 16 + l4 * 4;
      short4v vv;
      for (int r = 0; r < 4; ++r) {
        const int row = rowb + r;
        const float qv = accq[rt][ct][r] + bvq[ct];
        const float kv = acck[rt][ct][r] + bvk[ct];
        const float sp = fmaxf(kv, 0.f) + __logf(1.f + __expf(-fabsf(kv)));
        q_out[(size_t)row * D_ + col] = __float2bfloat16(qv);
        kt_out[(size_t)row * D_ + col] = __float2bfloat16(sp);
        vv[r] = f2bs(qv + kv);
      }
      const int b = rowb >> 11, s = rowb & 2047;
      // key swizzle p(k) within 64-chunk; s%4==0 -> 4 consecutive stay together
      const int sw = (s & ~63) | (((s >> 4) & 3) << 2) | (((s >> 2) & 3) << 4);
      *(short4v*)(vT + ((size_t)(b * H_ + h) * HD_ + d) * S_ + sw) = vv;
    }
}

// ------- Stage D: flash attention — XCD-pinned, 128-key chunks.
// r16: latency-bound fix (MfmaUtil 35%, nothing saturated, 2 waves/SIMD
// structural cap): software-pipeline the two 64-key subchunks. All K(u0)+
// V(u0)+K(u1) ds_reads issued up front; QK(u1) and PV(u0) share one
// scheduling region (independent -> fills exp->pack->PV latency);
// s_setprio(1) around MFMA clusters (T5). VGPR headroom is free (LDS caps
// occupancy at 2 blocks/CU, budget 256).
__global__ __launch_bounds__(256, 2) void attn(
    const __hip_bfloat16* __restrict__ qb, const __hip_bfloat16* __restrict__ ktb,
    const __hip_bfloat16* __restrict__ vT, const int* __restrict__ mask,
    float* __restrict__ out) {
  // buffer: kt0[4096] kt1[4096] v0[4096] v1[4096] shorts; 2 bufs = 65536 B
  __shared__ short smem[32768];
  const int id = blockIdx.x;
  const int xcd = id & 7;
  const int rest = id >> 3;              // 0..63
  const int q0 = (rest & 15) * 128;      // q-tile
  const int hb = (rest >> 4) * 8 + xcd;  // 0..31
  const int h = hb >> 1, b = hb & 1;
  const int tid = threadIdx.x, wid = tid >> 6, lane = tid & 63;
  const int l15 = lane & 15, l4 = lane >> 4;
  const __hip_bfloat16* qh = qb + (size_t)b * S_ * D_ + h * HD_;
  const __hip_bfloat16* kh = ktb + (size_t)b * S_ * D_ + h * HD_;
  const __hip_bfloat16* vh = vT + (size_t)(b * H_ + h) * HD_ * S_;
  // staging map: row=tid>>2 (0..63), two 16B blocks b0=(tid&3), b0+4
  const int srow = tid >> 2;
  const int b0 = tid & 3;
  const int sh = srow & 7;
  const int w0 = srow * 64 + ((b0 ^ sh) * 8);
  const int w1 = srow * 64 + (((b0 + 4) ^ sh) * 8);

  // q B-fragments for tiles A,B; mask*scale*log2e folded in
  const int qlA = wid * 32 + l15, qlB = qlA + 16;
  const int qrA = q0 + qlA, qrB = q0 + qlB;
  const float SC = 0.125f * 1.44269504f;
  const float mqA = (mask[b * S_ + qrA] != 0) ? SC : 0.f;
  const float mqB = (mask[b * S_ + qrB] != 0) ? SC : 0.f;
  const short8 rA0 = *(const short8*)(qh + (size_t)qrA * D_ + l4 * 8);
  const short8 rA1 = *(const short8*)(qh + (size_t)qrA * D_ + 32 + l4 * 8);
  const short8 rB0 = *(const short8*)(qh + (size_t)qrB * D_ + l4 * 8);
  const short8 rB1 = *(const short8*)(qh + (size_t)qrB * D_ + 32 + l4 * 8);
  short8 bqA0, bqA1, bqB0, bqB1;
  for (int j = 0; j < 8; ++j) {
    bqA0[j] = f2bs(bs2f(rA0[j]) * mqA);
    bqA1[j] = f2bs(bs2f(rA1[j]) * mqA);
    bqB0[j] = f2bs(bs2f(rB0[j]) * mqB);
    bqB1[j] = f2bs(bs2f(rB1[j]) * mqB);
  }

  // fragment read offsets (XOR-swizzled)
  const int lsh = l15 & 7;
  const int ak0off = l15 * 64 + ((l4 ^ lsh) * 8);          // + u*4096 + t*1024
  const int ak1off = l15 * 64 + (((l4 + 4) ^ lsh) * 8);
  const int vb0off = ((2 * l4) ^ lsh) * 8;                 // + 8192 + u*4096 + row*64
  const int vb1off = ((2 * l4 + 1) ^ lsh) * 8;

  const float4v zz = {0.f, 0.f, 0.f, 0.f};
  float4v oaccA[4] = {zz, zz, zz, zz};
  float4v oaccB[4] = {zz, zz, zz, zz};
  float lsumA = 0.f, lsumB = 0.f;

  // prefetch chunk 0 (two 64-key subchunks)
  short8 gk0[2], gk1[2], gv0[2], gv1[2];
#pragma unroll
  for (int u = 0; u < 2; ++u) {
    gk0[u] = *(const short8*)(kh + (size_t)(u * 64 + srow) * D_ + b0 * 8);
    gk1[u] = *(const short8*)(kh + (size_t)(u * 64 + srow) * D_ + b0 * 8 + 32);
    gv0[u] = *(const short8*)(vh + (size_t)srow * S_ + u * 64 + b0 * 8);
    gv1[u] = *(const short8*)(vh + (size_t)srow * S_ + u * 64 + b0 * 8 + 32);
  }

  int p = 0;
  for (int c = 0; c < 16; ++c) {
    short* bufp = smem + p * 16384;
#pragma unroll
    for (int u = 0; u < 2; ++u) {
      *(short8*)(bufp + u * 4096 + w0) = gk0[u];
      *(short8*)(bufp + u * 4096 + w1) = gk1[u];
      *(short8*)(bufp + 8192 + u * 4096 + w0) = gv0[u];
      *(short8*)(bufp + 8192 + u * 4096 + w1) = gv1[u];
    }
    __syncthreads();
    if (c < 15) {
      const int kb = (c + 1) * 128;
#pragma unroll
      for (int u = 0; u < 2; ++u) {
        gk0[u] = *(const short8*)(kh + (size_t)(kb + u * 64 + srow) * D_ + b0 * 8);
        gk1[u] = *(const short8*)(kh + (size_t)(kb + u * 64 + srow) * D_ + b0 * 8 + 32);
        gv0[u] = *(const short8*)(vh + (size_t)srow * S_ + kb + u * 64 + b0 * 8);
        gv1[u] = *(const short8*)(vh + (size_t)srow * S_ + kb + u * 64 + b0 * 8 + 32);
      }
    }
    const short* k0b = bufp;            // K subchunk u=0
    const short* k1b = bufp + 4096;     // K subchunk u=1
    const short* v0b = bufp + 8192;     // V subchunk u=0
    const short* v1b = bufp + 12288;    // V subchunk u=1

    // ---- issue fragment reads: K(u0), V(u0), K(u1) all in flight ----
    short8 ak0_0[4], ak1_0[4], ak0_1[4], ak1_1[4];
    short8 av0_0[4], av1_0[4], av0_1[4], av1_1[4];
#pragma unroll
    for (int t = 0; t < 4; ++t) {
      ak0_0[t] = *(const short8*)(k0b + t * 1024 + ak0off);
      ak1_0[t] = *(const short8*)(k0b + t * 1024 + ak1off);
    }
#pragma unroll
    for (int dt = 0; dt < 4; ++dt) {
      const int rb = (dt * 16 + l15) * 64;
      av0_0[dt] = *(const short8*)(v0b + rb + vb0off);
      av1_0[dt] = *(const short8*)(v0b + rb + vb1off);
    }
#pragma unroll
    for (int t = 0; t < 4; ++t) {
      ak0_1[t] = *(const short8*)(k1b + t * 1024 + ak0off);
      ak1_1[t] = *(const short8*)(k1b + t * 1024 + ak1off);
    }

    // ---- QK(u0) ----
    float4v c0A[4], c0B[4];
    __builtin_amdgcn_s_setprio(1);
#pragma unroll
    for (int t = 0; t < 4; ++t) {
      float4v cA = zz, cB = zz;
      cA = mfma32(ak0_0[t], bqA0, cA);
      cA = mfma32(ak1_0[t], bqA1, cA);
      cB = mfma32(ak0_0[t], bqB0, cB);
      cB = mfma32(ak1_0[t], bqB1, cB);
      c0A[t] = cA; c0B[t] = cB;
    }
    __builtin_amdgcn_s_setprio(0);
    // ---- exp/pack(u0) ----
    short4v pA0[4], pB0[4];
#pragma unroll
    for (int t = 0; t < 4; ++t) {
      float eA[4], eB[4];
#pragma unroll
      for (int r = 0; r < 4; ++r) {
        eA[r] = __builtin_amdgcn_exp2f(c0A[t][r]); lsumA += eA[r];
        eB[r] = __builtin_amdgcn_exp2f(c0B[t][r]); lsumB += eB[r];
      }
      pA0[t] = pk4(eA[0], eA[1], eA[2], eA[3]);
      pB0[t] = pk4(eB[0], eB[1], eB[2], eB[3]);
    }
    // ---- issue V(u1) reads ----
#pragma unroll
    for (int dt = 0; dt < 4; ++dt) {
      const int rb = (dt * 16 + l15) * 64;
      av0_1[dt] = *(const short8*)(v1b + rb + vb0off);
      av1_1[dt] = *(const short8*)(v1b + rb + vb1off);
    }
    // ---- QK(u1) + PV(u0): independent, one scheduling region ----
    float4v c1A[4], c1B[4];
    __builtin_amdgcn_s_setprio(1);
#pragma unroll
    for (int t = 0; t < 4; ++t) {
      float4v cA = zz, cB = zz;
      cA = mfma32(ak0_1[t], bqA0, cA);
      cA = mfma32(ak1_1[t], bqA1, cA);
      cB = mfma32(ak0_1[t], bqB0, cB);
      cB = mfma32(ak1_1[t], bqB1, cB);
      c1A[t] = cA; c1B[t] = cB;
    }
#pragma unroll
    for (int dt = 0; dt < 4; ++dt) {
      const short4v a0 = {av0_0[dt][0], av0_0[dt][1], av0_0[dt][2], av0_0[dt][3]};
      const short4v a1 = {av0_0[dt][4], av0_0[dt][5], av0_0[dt][6], av0_0[dt][7]};
      const short4v a2 = {av1_0[dt][0], av1_0[dt][1], av1_0[dt][2], av1_0[dt][3]};
      const short4v a3 = {av1_0[dt][4], av1_0[dt][5], av1_0[dt][6], av1_0[dt][7]};
      oaccA[dt] = mfma16(a0, pA0[0], oaccA[dt]);
      oaccB[dt] = mfma16(a0, pB0[0], oaccB[dt]);
      oaccA[dt] = mfma16(a1, pA0[1], oaccA[dt]);
      oaccB[dt] = mfma16(a1, pB0[1], oaccB[dt]);
      oaccA[dt] = mfma16(a2, pA0[2], oaccA[dt]);
      oaccB[dt] = mfma16(a2, pB0[2], oaccB[dt]);
      oaccA[dt] = mfma16(a3, pA0[3], oaccA[dt]);
      oaccB[dt] = mfma16(a3, pB0[3], oaccB[dt]);
    }
    __builtin_amdgcn_s_setprio(0);
    // ---- exp/pack(u1) ----
    short4v pA1[4], pB1[4];
#pragma unroll
    for (int t = 0; t < 4; ++t) {
      float eA[4], eB[4];
#pragma unroll
      for (int r = 0; r < 4; ++r) {
        eA[r] = __builtin_amdgcn_exp2f(c1A[t][r]); lsumA += eA[r];
        eB[r] = __builtin_amdgcn_exp2f(c1B[t][r]); lsumB += eB[r];
      }
      pA1[t] = pk4(eA[0], eA[1], eA[2], eA[3]);
      pB1[t] = pk4(eB[0], eB[1], eB[2], eB[3]);
    }
    // ---- PV(u1) ----
    __builtin_amdgcn_s_setprio(1);
#pragma unroll
    for (int dt = 0; dt < 4; ++dt) {
      const short4v a0 = {av0_1[dt][0], av0_1[dt][1], av0_1[dt][2], av0_1[dt][3]};
      const short4v a1 = {av0_1[dt][4], av0_1[dt][5], av0_1[dt][6], av0_1[dt][7]};
      const short4v a2 = {av1_1[dt][0], av1_1[dt][1], av1_1[dt][2], av1_1[dt][3]};
      const short4v a3 = {av1_1[dt][4], av1_1[dt][5], av1_1[dt][6], av1_1[dt][7]};
      oaccA[dt] = mfma16(a0, pA1[0], oaccA[dt]);
      oaccB[dt] = mfma16(a0, pB1[0], oaccB[dt]);
      oaccA[dt] = mfma16(a1, pA1[1], oaccA[dt]);
      oaccB[dt] = mfma16(a1, pB1[1], oaccB[dt]);
      oaccA[dt] = mfma16(a2, pA1[2], oaccA[dt]);
      oaccB[dt] = mfma16(a2, pB1[2], oaccB[dt]);
      oaccA[dt] = mfma16(a3, pA1[3], oaccA[dt]);
      oaccB[dt] = mfma16(a3, pB1[3], oaccB[dt]);
    }
    __builtin_amdgcn_s_setprio(0);
    p ^= 1;
  }
  // ---- epilogue: quad-reduce l; LDS transpose for coalesced stores ----
  float lA = lsumA + __shfl_xor(lsumA, 16); lA += __shfl_xor(lA, 32);
  float lB = lsumB + __shfl_xor(lsumB, 16); lB += __shfl_xor(lB, 32);
  __syncthreads();
  float* mbuf = (float*)smem;            // [128][68]
  float* mlb = (float*)smem + 128 * 68;  // [128]
#pragma unroll
  for (int dt = 0; dt < 4; ++dt)
#pragma unroll
    for (int r = 0; r < 4; ++r) {
      mbuf[qlA * 68 + dt * 16 + l4 * 4 + r] = oaccA[dt][r];
      mbuf[qlB * 68 + dt * 16 + l4 * 4 + r] = oaccB[dt][r];
    }
  if (l4 == 0) { mlb[qlA] = lA; mlb[qlB] = lB; }
  __syncthreads();
  const int qq = tid >> 1;
  const int dg = (tid & 1) * 32;
  const float li = 1.f / mlb[qq];
  float* orow = out + (size_t)(b * S_ + q0 + qq) * D_ + h * HD_ + dg;
#pragma unroll
  for (int i = 0; i < 8; ++i) {
    float4v v = *(const float4v*)&mbuf[qq * 68 + dg + i * 4];
#pragma unroll
    for (int r = 0; r < 4; ++r) v[r] *= li;
    *(float4v*)(orow + i * 4) = v;
  }
}

extern "C" void kernel_launch(void* const* d_in, const int* in_sizes, int n_in,
                              void* d_out, int out_size, void* d_ws, size_t ws_size,
                              hipStream_t stream) {
  const float* hs = (const float*)d_in[0];
  const int* mask = (const int*)d_in[1];
  const float* Wq = (const float*)d_in[2];
  const float* bq = (const float*)d_in[3];
  const float* Wk = (const float*)d_in[4];
  const float* bk = (const float*)d_in[5];
  float* out = (float*)d_out;
  char* ws = (char*)d_ws;
  const size_t MB = 1u << 20;
  __hip_bfloat16* q_b = (__hip_bfloat16*)(ws + 0 * MB);   // [B,S,D] bf16, 8MB
  __hip_bfloat16* k_b = (__hip_bfloat16*)(ws + 8 * MB);   // softplus(k), 8MB
  __hip_bfloat16* vT  = (__hip_bfloat16*)(ws + 16 * MB);  // [B,H,HD,S] key-swizzled, 8MB
  __hip_bfloat16* Wqt = (__hip_bfloat16*)(ws + 24 * MB);  // 2MB
  __hip_bfloat16* Wkt = (__hip_bfloat16*)(ws + 26 * MB);  // 2MB

  pre<<<dim3(16, 16, 2), 256, 0, stream>>>(Wq, Wk, Wqt, Wkt);
  gemm_fused<<<dim3(256), 512, 0, stream>>>(hs, Wqt, Wkt, bq, bk, q_b, k_b, vT);
  attn<<<dim3(512), 256, 0, stream>>>(q_b, k_b, vT, mask, out);
}

// Round 2
// 161.354 us; speedup vs baseline: 1.0367x; 1.0367x over previous
//
#include <hip/hip_runtime.h>
#include <hip/hip_bf16.h>

#define B_ 2
#define S_ 2048
#define D_ 1024
#define H_ 16
#define HD_ 64

typedef __attribute__((ext_vector_type(8))) short short8;
typedef __attribute__((ext_vector_type(4))) short short4v;
typedef __attribute__((ext_vector_type(4))) float float4v;

typedef const __attribute__((address_space(1))) void* gas_ptr;
typedef __attribute__((address_space(3))) void* las_ptr;

static __device__ inline void gl_lds16(const void* g, void* l) {
  __builtin_amdgcn_global_load_lds((gas_ptr)g, (las_ptr)l, 16, 0, 0);
}

static __device__ inline float b2f(__hip_bfloat16 h) { return __bfloat162float(h); }

static __device__ inline short f2bs(float x) {
  __hip_bfloat16 h = __float2bfloat16(x);
  union { __hip_bfloat16 h; short s; } u; u.h = h; return u.s;
}
static __device__ inline float bs2f(short s) {
  union { short s; __hip_bfloat16 h; } u; u.s = s; return __bfloat162float(u.h);
}
// packed f32x4 -> bf16x4 (v_cvt_pk_bf16_f32 x2)
static __device__ inline short4v pk4(float a, float b, float c, float d) {
  union { __hip_bfloat162 h[2]; short4v s; } u;
  u.h[0] = __float22bfloat162_rn(float2{a, b});
  u.h[1] = __float22bfloat162_rn(float2{c, d});
  return u.s;
}

static __device__ inline float4v mfma32(short8 a, short8 b, float4v c) {
  return __builtin_amdgcn_mfma_f32_16x16x32_bf16(a, b, c, 0, 0, 0);
}
// v_mfma_f32_16x16x16_bf16 — "_1k" builtin, present on gfx950.
static __device__ inline float4v mfma16(short4v a, short4v b, float4v c) {
  return __builtin_amdgcn_mfma_f32_16x16x16bf16_1k(a, b, c, 0, 0, 0);
}

// ------- Stage A0: hs fp32 -> bf16 (memory-bound, ~4 us). Lets gemm stage A
// via global_load_lds (no per-iter cvt VALU, half the A bytes). -------
__global__ __launch_bounds__(256) void cvt(
    const float* __restrict__ in, __hip_bfloat16* __restrict__ out) {
  const size_t i = ((size_t)blockIdx.x * 256 + threadIdx.x) * 8;
  const float4v a0 = ((const float4v*)(in + i))[0];
  const float4v a1 = ((const float4v*)(in + i))[1];
  short8 s;
#pragma unroll
  for (int j = 0; j < 4; ++j) { s[j] = f2bs(a0[j]); s[4 + j] = f2bs(a1[j]); }
  *(short8*)(out + i) = s;
}

// ------- Stage A: W fp32 [k][n] -> Wt bf16 [n][k] -------
__global__ __launch_bounds__(256) void pre(
    const float* __restrict__ Wq, const float* __restrict__ Wk,
    __hip_bfloat16* __restrict__ Wqt, __hip_bfloat16* __restrict__ Wkt) {
  const float* W = blockIdx.z ? Wk : Wq;
  __hip_bfloat16* Wt = blockIdx.z ? Wkt : Wqt;
  __shared__ float t[64][65];
  const int n0 = blockIdx.x * 64, k0 = blockIdx.y * 64;
  const int c = threadIdx.x & 63, r0 = threadIdx.x >> 6;
  for (int i = 0; i < 16; ++i) {
    const int r = i * 4 + r0;
    t[c][r] = W[(size_t)(k0 + r) * D_ + n0 + c];
  }
  __syncthreads();
  for (int i = 0; i < 16; ++i) {
    const int rr = i * 4 + r0;
    Wt[(size_t)(n0 + rr) * D_ + k0 + c] = __float2bfloat16(t[rr][c]);
  }
}

// ---- Stage B (fused GEMM+prep): 128x128 tile, 512 thr / 8 waves, XCD-PINNED.
// r17: (1) A now bf16, staged via gl_lds16 like B (no per-iter cvt VALU).
// (2) T2 conflict fix: the [128][32] bf16 tile read as b128 per row was a
// 4-way quad conflict (64B row stride -> rows alternate quads {0,4}).
// gl_lds writes linearly, so the swizzle is applied on the GLOBAL source
// chunk (g = c ^ ((row>>1)&3), rule #21) and inverted on the ds_read offset.
__global__ __launch_bounds__(512, 2) void gemm_fused(
    const __hip_bfloat16* __restrict__ hsb,
    const __hip_bfloat16* __restrict__ Wqt, const __hip_bfloat16* __restrict__ Wkt,
    const float* __restrict__ bq, const float* __restrict__ bk,
    __hip_bfloat16* __restrict__ q_out, __hip_bfloat16* __restrict__ kt_out,
    __hip_bfloat16* __restrict__ vT) {
  const int id = blockIdx.x;
  const int mt = (id & 7) * 4 + ((id >> 3) & 3);  // m-tile 0..31, pinned by xcd
  const int nt = id >> 5;                          // n-block 0..7
  const int n0 = nt * 128, m0 = mt * 128;
  __shared__ __hip_bfloat16 As[2][128 * 32];
  __shared__ __hip_bfloat16 Bq[2][128 * 32];
  __shared__ __hip_bfloat16 Bk[2][128 * 32];
  const int tid = threadIdx.x, wid = tid >> 6, lane = tid & 63;
  const int wm = (wid >> 1) * 32, wn = (wid & 1) * 64;
  const int l15 = lane & 15, l4 = lane >> 4;
  const float4v zz = {0.f, 0.f, 0.f, 0.f};
  float4v accq[2][4], acck[2][4];
  for (int i = 0; i < 2; ++i)
    for (int j = 0; j < 4; ++j) { accq[i][j] = zz; acck[i][j] = zz; }
  const int lrow = wid * 16 + (lane >> 2);
  // source-swizzled chunk: LDS chunk (lane&3) of row (lane>>2) gets global
  // chunk (lane&3) ^ ((row>>1)&3)
  const int lk8 = (((lane & 3) ^ ((lane >> 3) & 3)) * 8);
  // preload chunk 0
  {
    gl_lds16(hsb + (size_t)(m0 + lrow) * D_ + lk8, As[0] + wid * 512);
    gl_lds16(Wqt + (size_t)(n0 + lrow) * D_ + lk8, Bq[0] + wid * 512);
    gl_lds16(Wkt + (size_t)(n0 + lrow) * D_ + lk8, Bk[0] + wid * 512);
  }
  int p = 0;
  for (int kb = 0; kb < 32; ++kb) {
    __syncthreads();  // buf[p] staged (vm drained); prev frag reads done
    if (kb < 31) {
      const int kc = (kb + 1) * 32 + lk8;
      gl_lds16(hsb + (size_t)(m0 + lrow) * D_ + kc, As[p ^ 1] + wid * 512);
      gl_lds16(Wqt + (size_t)(n0 + lrow) * D_ + kc, Bq[p ^ 1] + wid * 512);
      gl_lds16(Wkt + (size_t)(n0 + lrow) * D_ + kc, Bk[p ^ 1] + wid * 512);
    }
    short8 af[2], bfq[4], bfk[4];
    const int fo = ((l4 ^ ((l15 >> 1) & 3)) * 8);  // de-swizzle on read
    for (int rt = 0; rt < 2; ++rt)
      af[rt] = *(const short8*)(As[p] + (wm + rt * 16 + l15) * 32 + fo);
    for (int ct = 0; ct < 4; ++ct) {
      bfq[ct] = *(const short8*)(Bq[p] + (wn + ct * 16 + l15) * 32 + fo);
      bfk[ct] = *(const short8*)(Bk[p] + (wn + ct * 16 + l15) * 32 + fo);
    }
    for (int rt = 0; rt < 2; ++rt)
      for (int ct = 0; ct < 4; ++ct) {
        accq[rt][ct] = mfma32(af[rt], bfq[ct], accq[rt][ct]);
        acck[rt][ct] = mfma32(af[rt], bfk[ct], acck[rt][ct]);
      }
    p ^= 1;
  }
  float bvq[4], bvk[4];
  for (int ct = 0; ct < 4; ++ct) {
    bvq[ct] = bq[n0 + wn + ct * 16 + l15];
    bvk[ct] = bk[n0 + wn + ct * 16 + l15];
  }
  for (int rt = 0; rt < 2; ++rt)
    for (int ct = 0; ct < 4; ++ct) {
      const int col = n0 + wn + ct * 16 + l15;
      const int h = col >> 6, d = col & 63;
      const int rowb = m0 + wm + rt * 16 + l4 * 4;
      short4v vv;
      for (int r = 0; r < 4; ++r) {
        const int row = rowb + r;
        const float qv = accq[rt][ct][r] + bvq[ct];
        const float kv = acck[rt][ct][r] + bvk[ct];
        const float sp = fmaxf(kv, 0.f) + __logf(1.f + __expf(-fabsf(kv)));
        q_out[(size_t)row * D_ + col] = __float2bfloat16(qv);
        kt_out[(size_t)row * D_ + col] = __float2bfloat16(sp);
        vv[r] = f2bs(qv + kv);
      }
      const int b = rowb >> 11, s = rowb & 2047;
      // key swizzle p(k) within 64-chunk; s%4==0 -> 4 consecutive stay together
      const int sw = (s & ~63) | (((s >> 4) & 3) << 2) | (((s >> 2) & 3) << 4);
      *(short4v*)(vT + ((size_t)(b * H_ + h) * HD_ + d) * S_ + sw) = vv;
    }
}

// ------- Stage D: flash attention — XCD-pinned, 128-key chunks (r15 schedule).
// r17: staging-WRITE bank fix. Old chunk map c = g ^ (row&7) put write-cycle
// lanes (rows r,r+1, 2-bit g) in only 4 bank-quads -> 2-way conflict on every
// ds_write_b128 (the 4.19M SQ_LDS_BANK_CONFLICT). New map s(r)=((r&1)<<2)|
// ((r>>1)&3): even/odd rows land in disjoint quad halves -> writes conflict-
// free; reads remain conflict-free (8 distinct quads per cycle group).
__global__ __launch_bounds__(256, 2) void attn(
    const __hip_bfloat16* __restrict__ qb, const __hip_bfloat16* __restrict__ ktb,
    const __hip_bfloat16* __restrict__ vT, const int* __restrict__ mask,
    float* __restrict__ out) {
  // buffer: kt0[4096] kt1[4096] v0[4096] v1[4096] shorts; 2 bufs = 65536 B
  __shared__ short smem[32768];
  const int id = blockIdx.x;
  const int xcd = id & 7;
  const int rest = id >> 3;              // 0..63
  const int q0 = (rest & 15) * 128;      // q-tile
  const int hb = (rest >> 4) * 8 + xcd;  // 0..31
  const int h = hb >> 1, b = hb & 1;
  const int tid = threadIdx.x, wid = tid >> 6, lane = tid & 63;
  const int l15 = lane & 15, l4 = lane >> 4;
  const __hip_bfloat16* qh = qb + (size_t)b * S_ * D_ + h * HD_;
  const __hip_bfloat16* kh = ktb + (size_t)b * S_ * D_ + h * HD_;
  const __hip_bfloat16* vh = vT + (size_t)(b * H_ + h) * HD_ * S_;
  // staging map: row=tid>>2 (0..63), two 16B blocks b0=(tid&3), b0+4
  const int srow = tid >> 2;
  const int b0 = tid & 3;
  const int ssw = ((srow & 1) << 2) | ((srow >> 1) & 3);  // s(row)
  const int w0 = srow * 64 + ((b0 ^ ssw) * 8);
  const int w1 = srow * 64 + (((b0 + 4) ^ ssw) * 8);

  // q B-fragments for tiles A,B; mask*scale*log2e folded in
  const int qlA = wid * 32 + l15, qlB = qlA + 16;
  const int qrA = q0 + qlA, qrB = q0 + qlB;
  const float SC = 0.125f * 1.44269504f;
  const float mqA = (mask[b * S_ + qrA] != 0) ? SC : 0.f;
  const float mqB = (mask[b * S_ + qrB] != 0) ? SC : 0.f;
  const short8 rA0 = *(const short8*)(qh + (size_t)qrA * D_ + l4 * 8);
  const short8 rA1 = *(const short8*)(qh + (size_t)qrA * D_ + 32 + l4 * 8);
  const short8 rB0 = *(const short8*)(qh + (size_t)qrB * D_ + l4 * 8);
  const short8 rB1 = *(const short8*)(qh + (size_t)qrB * D_ + 32 + l4 * 8);
  short8 bqA0, bqA1, bqB0, bqB1;
  for (int j = 0; j < 8; ++j) {
    bqA0[j] = f2bs(bs2f(rA0[j]) * mqA);
    bqA1[j] = f2bs(bs2f(rA1[j]) * mqA);
    bqB0[j] = f2bs(bs2f(rB0[j]) * mqB);
    bqB1[j] = f2bs(bs2f(rB1[j]) * mqB);
  }

  // fragment read offsets (s(row)-swizzled; row&7 == l15&7 for all reads)
  const int lsw = ((l15 & 1) << 2) | ((l15 >> 1) & 3);
  const int ak0off = l15 * 64 + ((l4 ^ lsw) * 8);          // + u*4096 + t*1024
  const int ak1off = l15 * 64 + (((l4 + 4) ^ lsw) * 8);
  const int vb0off = ((2 * l4) ^ lsw) * 8;                 // + 8192 + u*4096 + row*64
  const int vb1off = ((2 * l4 + 1) ^ lsw) * 8;

  const float4v zz = {0.f, 0.f, 0.f, 0.f};
  float4v oaccA[4] = {zz, zz, zz, zz};
  float4v oaccB[4] = {zz, zz, zz, zz};
  float lsumA = 0.f, lsumB = 0.f;

  // prefetch chunk 0 (two 64-key subchunks)
  short8 gk0[2], gk1[2], gv0[2], gv1[2];
#pragma unroll
  for (int u = 0; u < 2; ++u) {
    gk0[u] = *(const short8*)(kh + (size_t)(u * 64 + srow) * D_ + b0 * 8);
    gk1[u] = *(const short8*)(kh + (size_t)(u * 64 + srow) * D_ + b0 * 8 + 32);
    gv0[u] = *(const short8*)(vh + (size_t)srow * S_ + u * 64 + b0 * 8);
    gv1[u] = *(const short8*)(vh + (size_t)srow * S_ + u * 64 + b0 * 8 + 32);
  }

  int p = 0;
  for (int c = 0; c < 16; ++c) {
    short* bufp = smem + p * 16384;
#pragma unroll
    for (int u = 0; u < 2; ++u) {
      *(short8*)(bufp + u * 4096 + w0) = gk0[u];
      *(short8*)(bufp + u * 4096 + w1) = gk1[u];
      *(short8*)(bufp + 8192 + u * 4096 + w0) = gv0[u];
      *(short8*)(bufp + 8192 + u * 4096 + w1) = gv1[u];
    }
    __syncthreads();
    if (c < 15) {
      const int kb = (c + 1) * 128;
#pragma unroll
      for (int u = 0; u < 2; ++u) {
        gk0[u] = *(const short8*)(kh + (size_t)(kb + u * 64 + srow) * D_ + b0 * 8);
        gk1[u] = *(const short8*)(kh + (size_t)(kb + u * 64 + srow) * D_ + b0 * 8 + 32);
        gv0[u] = *(const short8*)(vh + (size_t)srow * S_ + kb + u * 64 + b0 * 8);
        gv1[u] = *(const short8*)(vh + (size_t)srow * S_ + kb + u * 64 + b0 * 8 + 32);
      }
    }
#pragma unroll
    for (int u = 0; u < 2; ++u) {  // 64-key subchunk
      const short* kbase = bufp + u * 4096;
      const short* vbase = bufp + 8192 + u * 4096;
      // ---- phase 1: QK for 4 key-tiles -> P fragments (exp2 domain) ----
      short4v pA[4], pB[4];
#pragma unroll
      for (int t = 0; t < 4; ++t) {
        const short8 ak0 = *(const short8*)(kbase + t * 1024 + ak0off);
        const short8 ak1 = *(const short8*)(kbase + t * 1024 + ak1off);
        float4v cA = zz, cB = zz;
        cA = mfma32(ak0, bqA0, cA);
        cA = mfma32(ak1, bqA1, cA);
        cB = mfma32(ak0, bqB0, cB);
        cB = mfma32(ak1, bqB1, cB);
        float eA[4], eB[4];
#pragma unroll
        for (int r = 0; r < 4; ++r) {
          eA[r] = __builtin_amdgcn_exp2f(cA[r]); lsumA += eA[r];
          eB[r] = __builtin_amdgcn_exp2f(cB[r]); lsumB += eB[r];
        }
        pA[t] = pk4(eA[0], eA[1], eA[2], eA[3]);
        pB[t] = pk4(eB[0], eB[1], eB[2], eB[3]);
      }
      // ---- phase 2: PV; 2x b128 per dt cover all 4 key-tiles (swizzled v) ----
#pragma unroll
      for (int dt = 0; dt < 4; ++dt) {
        const int rb = (dt * 16 + l15) * 64;
        const short8 av0 = *(const short8*)(vbase + rb + vb0off);
        const short8 av1 = *(const short8*)(vbase + rb + vb1off);
        const short4v a0 = {av0[0], av0[1], av0[2], av0[3]};
        const short4v a1 = {av0[4], av0[5], av0[6], av0[7]};
        const short4v a2 = {av1[0], av1[1], av1[2], av1[3]};
        const short4v a3 = {av1[4], av1[5], av1[6], av1[7]};
        oaccA[dt] = mfma16(a0, pA[0], oaccA[dt]);
        oaccB[dt] = mfma16(a0, pB[0], oaccB[dt]);
        oaccA[dt] = mfma16(a1, pA[1], oaccA[dt]);
        oaccB[dt] = mfma16(a1, pB[1], oaccB[dt]);
        oaccA[dt] = mfma16(a2, pA[2], oaccA[dt]);
        oaccB[dt] = mfma16(a2, pB[2], oaccB[dt]);
        oaccA[dt] = mfma16(a3, pA[3], oaccA[dt]);
        oaccB[dt] = mfma16(a3, pB[3], oaccB[dt]);
      }
    }
    p ^= 1;
  }
  // ---- epilogue: quad-reduce l; LDS transpose for coalesced stores ----
  float lA = lsumA + __shfl_xor(lsumA, 16); lA += __shfl_xor(lA, 32);
  float lB = lsumB + __shfl_xor(lsumB, 16); lB += __shfl_xor(lB, 32);
  __syncthreads();
  float* mbuf = (float*)smem;            // [128][68]
  float* mlb = (float*)smem + 128 * 68;  // [128]
#pragma unroll
  for (int dt = 0; dt < 4; ++dt)
#pragma unroll
    for (int r = 0; r < 4; ++r) {
      mbuf[qlA * 68 + dt * 16 + l4 * 4 + r] = oaccA[dt][r];
      mbuf[qlB * 68 + dt * 16 + l4 * 4 + r] = oaccB[dt][r];
    }
  if (l4 == 0) { mlb[qlA] = lA; mlb[qlB] = lB; }
  __syncthreads();
  const int qq = tid >> 1;
  const int dg = (tid & 1) * 32;
  const float li = 1.f / mlb[qq];
  float* orow = out + (size_t)(b * S_ + q0 + qq) * D_ + h * HD_ + dg;
#pragma unroll
  for (int i = 0; i < 8; ++i) {
    float4v v = *(const float4v*)&mbuf[qq * 68 + dg + i * 4];
#pragma unroll
    for (int r = 0; r < 4; ++r) v[r] *= li;
    *(float4v*)(orow + i * 4) = v;
  }
}

extern "C" void kernel_launch(void* const* d_in, const int* in_sizes, int n_in,
                              void* d_out, int out_size, void* d_ws, size_t ws_size,
                              hipStream_t stream) {
  const float* hs = (const float*)d_in[0];
  const int* mask = (const int*)d_in[1];
  const float* Wq = (const float*)d_in[2];
  const float* bq = (const float*)d_in[3];
  const float* Wk = (const float*)d_in[4];
  const float* bk = (const float*)d_in[5];
  float* out = (float*)d_out;
  char* ws = (char*)d_ws;
  const size_t MB = 1u << 20;
  __hip_bfloat16* q_b = (__hip_bfloat16*)(ws + 0 * MB);   // [B,S,D] bf16, 8MB
  __hip_bfloat16* k_b = (__hip_bfloat16*)(ws + 8 * MB);   // softplus(k), 8MB
  __hip_bfloat16* vT  = (__hip_bfloat16*)(ws + 16 * MB);  // [B,H,HD,S] key-swizzled, 8MB
  __hip_bfloat16* Wqt = (__hip_bfloat16*)(ws + 24 * MB);  // 2MB
  __hip_bfloat16* Wkt = (__hip_bfloat16*)(ws + 26 * MB);  // 2MB
  __hip_bfloat16* hsb = (__hip_bfloat16*)(ws + 28 * MB);  // [B,S,D] bf16, 8MB

  cvt<<<dim3(2048), 256, 0, stream>>>(hs, hsb);
  pre<<<dim3(16, 16, 2), 256, 0, stream>>>(Wq, Wk, Wqt, Wkt);
  gemm_fused<<<dim3(256), 512, 0, stream>>>(hsb, Wqt, Wkt, bq, bk, q_b, k_b, vT);
  attn<<<dim3(512), 256, 0, stream>>>(q_b, k_b, vT, mask, out);
}

// Round 3
// 158.607 us; speedup vs baseline: 1.0547x; 1.0173x over previous
//
#include <hip/hip_runtime.h>
#include <hip/hip_bf16.h>

#define B_ 2
#define S_ 2048
#define D_ 1024
#define H_ 16
#define HD_ 64

typedef __attribute__((ext_vector_type(8))) short short8;
typedef __attribute__((ext_vector_type(4))) short short4v;
typedef __attribute__((ext_vector_type(4))) float float4v;

typedef const __attribute__((address_space(1))) void* gas_ptr;
typedef __attribute__((address_space(3))) void* las_ptr;

static __device__ inline void gl_lds16(const void* g, void* l) {
  __builtin_amdgcn_global_load_lds((gas_ptr)g, (las_ptr)l, 16, 0, 0);
}

static __device__ inline short f2bs(float x) {
  __hip_bfloat16 h = __float2bfloat16(x);
  union { __hip_bfloat16 h; short s; } u; u.h = h; return u.s;
}
static __device__ inline float bs2f(short s) {
  union { short s; __hip_bfloat16 h; } u; u.s = s; return __bfloat162float(u.h);
}
// packed f32x4 -> bf16x4 (v_cvt_pk_bf16_f32 x2)
static __device__ inline short4v pk4(float a, float b, float c, float d) {
  union { __hip_bfloat162 h[2]; short4v s; } u;
  u.h[0] = __float22bfloat162_rn(float2{a, b});
  u.h[1] = __float22bfloat162_rn(float2{c, d});
  return u.s;
}

static __device__ inline float4v mfma32(short8 a, short8 b, float4v c) {
  return __builtin_amdgcn_mfma_f32_16x16x32_bf16(a, b, c, 0, 0, 0);
}
// v_mfma_f32_16x16x16_bf16 — "_1k" builtin, present on gfx950.
static __device__ inline float4v mfma16(short4v a, short4v b, float4v c) {
  return __builtin_amdgcn_mfma_f32_16x16x16bf16_1k(a, b, c, 0, 0, 0);
}

// ------- Stage A (merged): blocks [0,2048): hs fp32->bf16; blocks [2048,2560):
// W fp32 [k][n] -> Wt bf16 [n][k]. One launch instead of two. -------
__global__ __launch_bounds__(256) void prep(
    const float* __restrict__ hs, __hip_bfloat16* __restrict__ hsb,
    const float* __restrict__ Wq, const float* __restrict__ Wk,
    __hip_bfloat16* __restrict__ Wqt, __hip_bfloat16* __restrict__ Wkt) {
  __shared__ float t[64][65];
  const int id = blockIdx.x;
  if (id < 2048) {
    const size_t i = ((size_t)id * 256 + threadIdx.x) * 8;
    const float4v a0 = ((const float4v*)(hs + i))[0];
    const float4v a1 = ((const float4v*)(hs + i))[1];
    short8 s;
#pragma unroll
    for (int j = 0; j < 4; ++j) { s[j] = f2bs(a0[j]); s[4 + j] = f2bs(a1[j]); }
    *(short8*)(hsb + i) = s;
    return;
  }
  const int bid = id - 2048;
  const float* W = (bid >> 8) ? Wk : Wq;
  __hip_bfloat16* Wt = (bid >> 8) ? Wkt : Wqt;
  const int n0 = (bid & 15) * 64, k0 = ((bid >> 4) & 15) * 64;
  const int c = threadIdx.x & 63, r0 = threadIdx.x >> 6;
  for (int i = 0; i < 16; ++i) {
    const int r = i * 4 + r0;
    t[c][r] = W[(size_t)(k0 + r) * D_ + n0 + c];
  }
  __syncthreads();
  for (int i = 0; i < 16; ++i) {
    const int rr = i * 4 + r0;
    Wt[(size_t)(n0 + rr) * D_ + k0 + c] = __float2bfloat16(t[rr][c]);
  }
}

// ---- Stage B (fused GEMM+prep): r18 restructure for 2 blocks/CU.
// Old: 256 blocks x 512 thr (128x128 tile) = 1 block/CU -> every
// __syncthreads stalls the whole CU on the vmcnt(0) global_load_lds drain
// (m97/m114: the 128^2 structure NEEDS a co-resident block to overlap the
// barrier drain). New: 512 blocks x 256 thr (4 waves), 64x128 tile, 40KB LDS
// -> 2 independent blocks/CU; block A's drain overlaps block B's MFMA.
// Per-wave structure unchanged: 32x64 output per wave per output (q,k),
// 10 ds_read_b128 per 16 mfma32, T2 source-swizzled staging (rule #21).
__global__ __launch_bounds__(256, 2) void gemm_fused(
    const __hip_bfloat16* __restrict__ hsb,
    const __hip_bfloat16* __restrict__ Wqt, const __hip_bfloat16* __restrict__ Wkt,
    const float* __restrict__ bq, const float* __restrict__ bk,
    __hip_bfloat16* __restrict__ q_out, __hip_bfloat16* __restrict__ kt_out,
    __hip_bfloat16* __restrict__ vT) {
  const int id = blockIdx.x;
  const int mt = (id & 7) * 8 + ((id >> 3) & 7);  // m-tile 0..63, pinned by xcd
  const int nt = id >> 6;                          // n-block 0..7
  const int n0 = nt * 128, m0 = mt * 64;
  __shared__ __hip_bfloat16 As[2][64 * 32];    // 8KB
  __shared__ __hip_bfloat16 Bq[2][128 * 32];   // 16KB
  __shared__ __hip_bfloat16 Bk[2][128 * 32];   // 16KB
  const int tid = threadIdx.x, wid = tid >> 6, lane = tid & 63;
  const int wm = (wid >> 1) * 32, wn = (wid & 1) * 64;
  const int l15 = lane & 15, l4 = lane >> 4;
  const float4v zz = {0.f, 0.f, 0.f, 0.f};
  float4v accq[2][4], acck[2][4];
  for (int i = 0; i < 2; ++i)
    for (int j = 0; j < 4; ++j) { accq[i][j] = zz; acck[i][j] = zz; }
  // staging: each wave stages 16 rows per gl_lds16 (64 lanes x 16B = 16 rows
  // of 32 bf16). lane -> row wid*16 + (lane>>2), chunk lane&3; global chunk
  // source-swizzled: g = (lane&3) ^ ((lane>>3)&3)  [= ((row%16)>>1)&3]
  const int lrow = wid * 16 + (lane >> 2);
  const int lk8 = (((lane & 3) ^ ((lane >> 3) & 3)) * 8);
  // preload chunk 0: A 1 write, Bq 2 (rows 0-63, 64-127), Bk 2
  {
    gl_lds16(hsb + (size_t)(m0 + lrow) * D_ + lk8, As[0] + wid * 512);
    gl_lds16(Wqt + (size_t)(n0 + lrow) * D_ + lk8, Bq[0] + wid * 512);
    gl_lds16(Wqt + (size_t)(n0 + 64 + lrow) * D_ + lk8, Bq[0] + 2048 + wid * 512);
    gl_lds16(Wkt + (size_t)(n0 + lrow) * D_ + lk8, Bk[0] + wid * 512);
    gl_lds16(Wkt + (size_t)(n0 + 64 + lrow) * D_ + lk8, Bk[0] + 2048 + wid * 512);
  }
  int p = 0;
  for (int kb = 0; kb < 32; ++kb) {
    __syncthreads();  // buf[p] staged (vm drained); prev frag reads done
    if (kb < 31) {
      const int kc = (kb + 1) * 32 + lk8;
      gl_lds16(hsb + (size_t)(m0 + lrow) * D_ + kc, As[p ^ 1] + wid * 512);
      gl_lds16(Wqt + (size_t)(n0 + lrow) * D_ + kc, Bq[p ^ 1] + wid * 512);
      gl_lds16(Wqt + (size_t)(n0 + 64 + lrow) * D_ + kc, Bq[p ^ 1] + 2048 + wid * 512);
      gl_lds16(Wkt + (size_t)(n0 + lrow) * D_ + kc, Bk[p ^ 1] + wid * 512);
      gl_lds16(Wkt + (size_t)(n0 + 64 + lrow) * D_ + kc, Bk[p ^ 1] + 2048 + wid * 512);
    }
    short8 af[2], bfq[4], bfk[4];
    const int fo = ((l4 ^ ((l15 >> 1) & 3)) * 8);  // de-swizzle on read
    for (int rt = 0; rt < 2; ++rt)
      af[rt] = *(const short8*)(As[p] + (wm + rt * 16 + l15) * 32 + fo);
    for (int ct = 0; ct < 4; ++ct) {
      bfq[ct] = *(const short8*)(Bq[p] + (wn + ct * 16 + l15) * 32 + fo);
      bfk[ct] = *(const short8*)(Bk[p] + (wn + ct * 16 + l15) * 32 + fo);
    }
    for (int rt = 0; rt < 2; ++rt)
      for (int ct = 0; ct < 4; ++ct) {
        accq[rt][ct] = mfma32(af[rt], bfq[ct], accq[rt][ct]);
        acck[rt][ct] = mfma32(af[rt], bfk[ct], acck[rt][ct]);
      }
    p ^= 1;
  }
  float bvq[4], bvk[4];
  for (int ct = 0; ct < 4; ++ct) {
    bvq[ct] = bq[n0 + wn + ct * 16 + l15];
    bvk[ct] = bk[n0 + wn + ct * 16 + l15];
  }
  for (int rt = 0; rt < 2; ++rt)
    for (int ct = 0; ct < 4; ++ct) {
      const int col = n0 + wn + ct * 16 + l15;
      const int h = col >> 6, d = col & 63;
      const int rowb = m0 + wm + rt * 16 + l4 * 4;
      short4v vv;
      for (int r = 0; r < 4; ++r) {
        const int row = rowb + r;
        const float qv = accq[rt][ct][r] + bvq[ct];
        const float kv = acck[rt][ct][r] + bvk[ct];
        const float sp = fmaxf(kv, 0.f) + __logf(1.f + __expf(-fabsf(kv)));
        q_out[(size_t)row * D_ + col] = __float2bfloat16(qv);
        kt_out[(size_t)row * D_ + col] = __float2bfloat16(sp);
        vv[r] = f2bs(qv + kv);
      }
      const int b = rowb >> 11, s = rowb & 2047;
      // key swizzle p(k) within 64-chunk; s%4==0 -> 4 consecutive stay together
      const int sw = (s & ~63) | (((s >> 4) & 3) << 2) | (((s >> 2) & 3) << 4);
      *(short4v*)(vT + ((size_t)(b * H_ + h) * HD_ + d) * S_ + sw) = vv;
    }
}

// ------- Stage D: flash attention — XCD-pinned, 128-key chunks (r17). ----
__global__ __launch_bounds__(256, 2) void attn(
    const __hip_bfloat16* __restrict__ qb, const __hip_bfloat16* __restrict__ ktb,
    const __hip_bfloat16* __restrict__ vT, const int* __restrict__ mask,
    float* __restrict__ out) {
  // buffer: kt0[4096] kt1[4096] v0[4096] v1[4096] shorts; 2 bufs = 65536 B
  __shared__ short smem[32768];
  const int id = blockIdx.x;
  const int xcd = id & 7;
  const int rest = id >> 3;              // 0..63
  const int q0 = (rest & 15) * 128;      // q-tile
  const int hb = (rest >> 4) * 8 + xcd;  // 0..31
  const int h = hb >> 1, b = hb & 1;
  const int tid = threadIdx.x, wid = tid >> 6, lane = tid & 63;
  const int l15 = lane & 15, l4 = lane >> 4;
  const __hip_bfloat16* qh = qb + (size_t)b * S_ * D_ + h * HD_;
  const __hip_bfloat16* kh = ktb + (size_t)b * S_ * D_ + h * HD_;
  const __hip_bfloat16* vh = vT + (size_t)(b * H_ + h) * HD_ * S_;
  // staging map: row=tid>>2 (0..63), two 16B blocks b0=(tid&3), b0+4
  const int srow = tid >> 2;
  const int b0 = tid & 3;
  const int ssw = ((srow & 1) << 2) | ((srow >> 1) & 3);  // s(row)
  const int w0 = srow * 64 + ((b0 ^ ssw) * 8);
  const int w1 = srow * 64 + (((b0 + 4) ^ ssw) * 8);

  // q B-fragments for tiles A,B; mask*scale*log2e folded in
  const int qlA = wid * 32 + l15, qlB = qlA + 16;
  const int qrA = q0 + qlA, qrB = q0 + qlB;
  const float SC = 0.125f * 1.44269504f;
  const float mqA = (mask[b * S_ + qrA] != 0) ? SC : 0.f;
  const float mqB = (mask[b * S_ + qrB] != 0) ? SC : 0.f;
  const short8 rA0 = *(const short8*)(qh + (size_t)qrA * D_ + l4 * 8);
  const short8 rA1 = *(const short8*)(qh + (size_t)qrA * D_ + 32 + l4 * 8);
  const short8 rB0 = *(const short8*)(qh + (size_t)qrB * D_ + l4 * 8);
  const short8 rB1 = *(const short8*)(qh + (size_t)qrB * D_ + 32 + l4 * 8);
  short8 bqA0, bqA1, bqB0, bqB1;
  for (int j = 0; j < 8; ++j) {
    bqA0[j] = f2bs(bs2f(rA0[j]) * mqA);
    bqA1[j] = f2bs(bs2f(rA1[j]) * mqA);
    bqB0[j] = f2bs(bs2f(rB0[j]) * mqB);
    bqB1[j] = f2bs(bs2f(rB1[j]) * mqB);
  }

  // fragment read offsets (s(row)-swizzled; row&7 == l15&7 for all reads)
  const int lsw = ((l15 & 1) << 2) | ((l15 >> 1) & 3);
  const int ak0off = l15 * 64 + ((l4 ^ lsw) * 8);          // + u*4096 + t*1024
  const int ak1off = l15 * 64 + (((l4 + 4) ^ lsw) * 8);
  const int vb0off = ((2 * l4) ^ lsw) * 8;                 // + 8192 + u*4096 + row*64
  const int vb1off = ((2 * l4 + 1) ^ lsw) * 8;

  const float4v zz = {0.f, 0.f, 0.f, 0.f};
  float4v oaccA[4] = {zz, zz, zz, zz};
  float4v oaccB[4] = {zz, zz, zz, zz};
  float lsumA = 0.f, lsumB = 0.f;

  // prefetch chunk 0 (two 64-key subchunks)
  short8 gk0[2], gk1[2], gv0[2], gv1[2];
#pragma unroll
  for (int u = 0; u < 2; ++u) {
    gk0[u] = *(const short8*)(kh + (size_t)(u * 64 + srow) * D_ + b0 * 8);
    gk1[u] = *(const short8*)(kh + (size_t)(u * 64 + srow) * D_ + b0 * 8 + 32);
    gv0[u] = *(const short8*)(vh + (size_t)srow * S_ + u * 64 + b0 * 8);
    gv1[u] = *(const short8*)(vh + (size_t)srow * S_ + u * 64 + b0 * 8 + 32);
  }

  int p = 0;
  for (int c = 0; c < 16; ++c) {
    short* bufp = smem + p * 16384;
#pragma unroll
    for (int u = 0; u < 2; ++u) {
      *(short8*)(bufp + u * 4096 + w0) = gk0[u];
      *(short8*)(bufp + u * 4096 + w1) = gk1[u];
      *(short8*)(bufp + 8192 + u * 4096 + w0) = gv0[u];
      *(short8*)(bufp + 8192 + u * 4096 + w1) = gv1[u];
    }
    __syncthreads();
    if (c < 15) {
      const int kb = (c + 1) * 128;
#pragma unroll
      for (int u = 0; u < 2; ++u) {
        gk0[u] = *(const short8*)(kh + (size_t)(kb + u * 64 + srow) * D_ + b0 * 8);
        gk1[u] = *(const short8*)(kh + (size_t)(kb + u * 64 + srow) * D_ + b0 * 8 + 32);
        gv0[u] = *(const short8*)(vh + (size_t)srow * S_ + kb + u * 64 + b0 * 8);
        gv1[u] = *(const short8*)(vh + (size_t)srow * S_ + kb + u * 64 + b0 * 8 + 32);
      }
    }
#pragma unroll
    for (int u = 0; u < 2; ++u) {  // 64-key subchunk
      const short* kbase = bufp + u * 4096;
      const short* vbase = bufp + 8192 + u * 4096;
      // ---- phase 1: QK for 4 key-tiles -> P fragments (exp2 domain) ----
      short4v pA[4], pB[4];
#pragma unroll
      for (int t = 0; t < 4; ++t) {
        const short8 ak0 = *(const short8*)(kbase + t * 1024 + ak0off);
        const short8 ak1 = *(const short8*)(kbase + t * 1024 + ak1off);
        float4v cA = zz, cB = zz;
        cA = mfma32(ak0, bqA0, cA);
        cA = mfma32(ak1, bqA1, cA);
        cB = mfma32(ak0, bqB0, cB);
        cB = mfma32(ak1, bqB1, cB);
        float eA[4], eB[4];
#pragma unroll
        for (int r = 0; r < 4; ++r) {
          eA[r] = __builtin_amdgcn_exp2f(cA[r]); lsumA += eA[r];
          eB[r] = __builtin_amdgcn_exp2f(cB[r]); lsumB += eB[r];
        }
        pA[t] = pk4(eA[0], eA[1], eA[2], eA[3]);
        pB[t] = pk4(eB[0], eB[1], eB[2], eB[3]);
      }
      // ---- phase 2: PV; 2x b128 per dt cover all 4 key-tiles (swizzled v) ----
#pragma unroll
      for (int dt = 0; dt < 4; ++dt) {
        const int rb = (dt * 16 + l15) * 64;
        const short8 av0 = *(const short8*)(vbase + rb + vb0off);
        const short8 av1 = *(const short8*)(vbase + rb + vb1off);
        const short4v a0 = {av0[0], av0[1], av0[2], av0[3]};
        const short4v a1 = {av0[4], av0[5], av0[6], av0[7]};
        const short4v a2 = {av1[0], av1[1], av1[2], av1[3]};
        const short4v a3 = {av1[4], av1[5], av1[6], av1[7]};
        oaccA[dt] = mfma16(a0, pA[0], oaccA[dt]);
        oaccB[dt] = mfma16(a0, pB[0], oaccB[dt]);
        oaccA[dt] = mfma16(a1, pA[1], oaccA[dt]);
        oaccB[dt] = mfma16(a1, pB[1], oaccB[dt]);
        oaccA[dt] = mfma16(a2, pA[2], oaccA[dt]);
        oaccB[dt] = mfma16(a2, pB[2], oaccB[dt]);
        oaccA[dt] = mfma16(a3, pA[3], oaccA[dt]);
        oaccB[dt] = mfma16(a3, pB[3], oaccB[dt]);
      }
    }
    p ^= 1;
  }
  // ---- epilogue: quad-reduce l; LDS transpose for coalesced stores ----
  float lA = lsumA + __shfl_xor(lsumA, 16); lA += __shfl_xor(lA, 32);
  float lB = lsumB + __shfl_xor(lsumB, 16); lB += __shfl_xor(lB, 32);
  __syncthreads();
  float* mbuf = (float*)smem;            // [128][68]
  float* mlb = (float*)smem + 128 * 68;  // [128]
#pragma unroll
  for (int dt = 0; dt < 4; ++dt)
#pragma unroll
    for (int r = 0; r < 4; ++r) {
      mbuf[qlA * 68 + dt * 16 + l4 * 4 + r] = oaccA[dt][r];
      mbuf[qlB * 68 + dt * 16 + l4 * 4 + r] = oaccB[dt][r];
    }
  if (l4 == 0) { mlb[qlA] = lA; mlb[qlB] = lB; }
  __syncthreads();
  const int qq = tid >> 1;
  const int dg = (tid & 1) * 32;
  const float li = 1.f / mlb[qq];
  float* orow = out + (size_t)(b * S_ + q0 + qq) * D_ + h * HD_ + dg;
#pragma unroll
  for (int i = 0; i < 8; ++i) {
    float4v v = *(const float4v*)&mbuf[qq * 68 + dg + i * 4];
#pragma unroll
    for (int r = 0; r < 4; ++r) v[r] *= li;
    *(float4v*)(orow + i * 4) = v;
  }
}

extern "C" void kernel_launch(void* const* d_in, const int* in_sizes, int n_in,
                              void* d_out, int out_size, void* d_ws, size_t ws_size,
                              hipStream_t stream) {
  const float* hs = (const float*)d_in[0];
  const int* mask = (const int*)d_in[1];
  const float* Wq = (const float*)d_in[2];
  const float* bq = (const float*)d_in[3];
  const float* Wk = (const float*)d_in[4];
  const float* bk = (const float*)d_in[5];
  float* out = (float*)d_out;
  char* ws = (char*)d_ws;
  const size_t MB = 1u << 20;
  __hip_bfloat16* q_b = (__hip_bfloat16*)(ws + 0 * MB);   // [B,S,D] bf16, 8MB
  __hip_bfloat16* k_b = (__hip_bfloat16*)(ws + 8 * MB);   // softplus(k), 8MB
  __hip_bfloat16* vT  = (__hip_bfloat16*)(ws + 16 * MB);  // [B,H,HD,S] key-swizzled, 8MB
  __hip_bfloat16* Wqt = (__hip_bfloat16*)(ws + 24 * MB);  // 2MB
  __hip_bfloat16* Wkt = (__hip_bfloat16*)(ws + 26 * MB);  // 2MB
  __hip_bfloat16* hsb = (__hip_bfloat16*)(ws + 28 * MB);  // [B,S,D] bf16, 8MB

  prep<<<dim3(2560), 256, 0, stream>>>(hs, hsb, Wq, Wk, Wqt, Wkt);
  gemm_fused<<<dim3(512), 256, 0, stream>>>(hsb, Wqt, Wkt, bq, bk, q_b, k_b, vT);
  attn<<<dim3(512), 256, 0, stream>>>(q_b, k_b, vT, mask, out);
}